// Round 6
// baseline (241.456 us; speedup 1.0000x reference)
//
#include <hip/hip_runtime.h>

// Centroid update: per-class mean of embed rows, blended with old centroid.
//   sums[c,:] = sum_{i: y[i]==c} embed[i,:]
//   out[c,:]  = 0.3 * sums[c,:]/count[c] + 0.7 * centroid[c,:]
//
// v6: statically-deep gather. Evidence: v0-v5 all land at 50-60 µs of
// kernel time over the ~156 µs harness fill floor, regardless of structure
// (rescan / counting-sort / G=4 / ping-pong). The one visible counter set
// (v4) showed VGPR=36, 938 GB/s, 15% duty: the compiler serialized every
// "deep" gather variant because the load loops had runtime trip counts and
// runtime-guarded conditional loads -> ~2 loads in flight, latency-bound.
// Fix: remove ALL runtime control flow from the hot loop.
//   - rows[] padded with rows[0] to a FIXED 64 iterations, fully unrolled
//     at compile time: 64 independent float4 loads, no branches. Pad loads
//     hit the same L1 line (no HBM cost); contribution corrected by
//     acc -= (64-m) * v(rows[0]) afterwards. P(m>64) ~ 1e-7 (Poisson(32.8));
//     a dynamic tail loop covers it anyway.
//   - 4 interleaved accumulators (static j&3 index) break the add chain.
//   - __launch_bounds__(256,4): VGPR cap 128 -> ~20 loads in flight/wave,
//     4 blocks/CU -> all 1000 blocks resident, 15.6 waves/CU.
// Per-CU outstanding ~125 KB >> 22 KB BW*latency -> BW-bound gather:
// 134 MB / 6.3 TB/s ~ 21 µs + ~5 µs scan. Fixed 64 loads/block also
// equalizes per-block work, killing the Poisson straggler tail.

#define BATCH       32768
#define EMBED_DIM   1024
#define NUM_CLASSES 1000
#define FACTOR      0.3f
#define MAXR        128    // capacity; Poisson(32.8) max ~60
#define NSTAT       64     // statically unrolled gather depth

__global__ __launch_bounds__(256, 4) void centroid_kernel(
    const float* __restrict__ embed,
    const int*   __restrict__ y,
    const float* __restrict__ centroid,
    float*       __restrict__ out)
{
    const int c   = blockIdx.x;      // class this block reduces
    const int tid = threadIdx.x;
    const int d0  = tid * 4;         // this thread's 4 dims (256*4 = 1024)

    __shared__ int rows[MAXR];       // matched row indices for class c
    __shared__ int nmatch;

    if (tid == 0) nmatch = 0;
    if (tid < NSTAT) rows[tid] = 0;  // safe pad base even if m == 0

    // Hoisted centroid load — overlaps the scan.
    const size_t o = (size_t)c * EMBED_DIM + d0;
    const float4 cen = *reinterpret_cast<const float4*>(centroid + o);

    __syncthreads();

    // ---- Scan: 32768 labels, coalesced int4, 8 loads in flight.
    // y is 128 KB -> L2-resident after first touch.
    #pragma unroll 8
    for (int base = 0; base < BATCH; base += 1024) {
        const int idx = base + d0;
        const int4 v = *reinterpret_cast<const int4*>(y + idx);
        if (v.x == c) { int p = atomicAdd(&nmatch, 1); rows[p] = idx + 0; }
        if (v.y == c) { int p = atomicAdd(&nmatch, 1); rows[p] = idx + 1; }
        if (v.z == c) { int p = atomicAdd(&nmatch, 1); rows[p] = idx + 2; }
        if (v.w == c) { int p = atomicAdd(&nmatch, 1); rows[p] = idx + 3; }
    }
    __syncthreads();

    const int m = nmatch;            // block-uniform (~33 avg, max ~60)

    // Pad rows[m..NSTAT) with rows[0] so the gather below is branch-free.
    // Pad loads re-hit rows[0]'s cache line; corrected after the loop.
    if (tid >= m && tid < NSTAT) rows[tid] = rows[0];
    __syncthreads();

    float4 accs[4];
    #pragma unroll
    for (int a = 0; a < 4; ++a) accs[a] = make_float4(0.f, 0.f, 0.f, 0.f);

    if (m > 0) {
        // ---- Gather: FIXED 64 fully-unrolled independent float4 loads.
        // No runtime branches -> compiler schedules deep (VGPR cap 128).
        #pragma unroll
        for (int j = 0; j < NSTAT; ++j) {
            const int r = rows[j];   // LDS broadcast — no bank conflict
            const float4 v = *reinterpret_cast<const float4*>(
                embed + (size_t)r * EMBED_DIM + d0);
            accs[j & 3].x += v.x; accs[j & 3].y += v.y;
            accs[j & 3].z += v.z; accs[j & 3].w += v.w;
        }
        // Remove pad contribution: pad count * row[0]'s value (L1 hit).
        if (m < NSTAT) {
            const float pad = (float)(NSTAT - m);
            const int r0 = rows[0];
            const float4 v0 = *reinterpret_cast<const float4*>(
                embed + (size_t)r0 * EMBED_DIM + d0);
            accs[0].x = fmaf(-pad, v0.x, accs[0].x);
            accs[0].y = fmaf(-pad, v0.y, accs[0].y);
            accs[0].z = fmaf(-pad, v0.z, accs[0].z);
            accs[0].w = fmaf(-pad, v0.w, accs[0].w);
        }
        // Dynamic tail for the (practically impossible) m > NSTAT case.
        for (int j = NSTAT; j < m; ++j) {
            const int r = rows[j];
            const float4 v = *reinterpret_cast<const float4*>(
                embed + (size_t)r * EMBED_DIM + d0);
            accs[1].x += v.x; accs[1].y += v.y;
            accs[1].z += v.z; accs[1].w += v.w;
        }
    }

    float4 acc;
    acc.x = (accs[0].x + accs[1].x) + (accs[2].x + accs[3].x);
    acc.y = (accs[0].y + accs[1].y) + (accs[2].y + accs[3].y);
    acc.z = (accs[0].z + accs[1].z) + (accs[2].z + accs[3].z);
    acc.w = (accs[0].w + accs[1].w) + (accs[2].w + accs[3].w);

    // ---- Epilogue: mean, blend, store. m==0 -> 0*inf = NaN, matching ref.
    const float inv = 1.0f / (float)m;
    float4 res;
    res.x = FACTOR * (acc.x * inv) + (1.0f - FACTOR) * cen.x;
    res.y = FACTOR * (acc.y * inv) + (1.0f - FACTOR) * cen.y;
    res.z = FACTOR * (acc.z * inv) + (1.0f - FACTOR) * cen.z;
    res.w = FACTOR * (acc.w * inv) + (1.0f - FACTOR) * cen.w;
    *reinterpret_cast<float4*>(out + o) = res;
}

extern "C" void kernel_launch(void* const* d_in, const int* in_sizes, int n_in,
                              void* d_out, int out_size, void* d_ws, size_t ws_size,
                              hipStream_t stream) {
    const float* embed    = (const float*)d_in[0];  // [32768, 1024]
    const int*   y        = (const int*)d_in[1];    // [32768] int32
    const float* centroid = (const float*)d_in[2];  // [1000, 1024]
    float*       out      = (float*)d_out;          // [1000, 1024]

    centroid_kernel<<<NUM_CLASSES, 256, 0, stream>>>(embed, y, centroid, out);
}

// Round 7
// 212.903 us; speedup vs baseline: 1.1341x; 1.1341x over previous
//
#include <hip/hip_runtime.h>

// Centroid update: per-class mean of embed rows, blended with old centroid.
//   sums[c,:] = sum_{i: y[i]==c} embed[i,:]
//   out[c,:]  = 0.3 * sums[c,:]/count[c] + 0.7 * centroid[c,:]
//
// v7: dim-split ×2 + register-sized bursts. Round-6 evidence: occupancy
// 9->36% doubled delivered BW (938->1951 GB/s) — parallelism is the right
// lever — but the 64-deep full unroll spilled (VGPR=64 alloc vs ~256 needed;
// WRITE_SIZE 90 MB vs 4 MB real output, +50 MB fetch) and traffic tripled.
// Fixes:
//  1. 2000 blocks: (class, dim-half). Each block owns 512 dims (float2 per
//     thread, 8 B/lane, 512 B/row/wave contiguous). Occupancy ceiling
//     49% -> ~98% (7.8 blocks/CU). Dims disjoint: no atomics, no combine
//     kernel, no extra HBM traffic. Scan runs 2x/class but is L2-served
//     (256 MB / 34.5 TB/s ~ 7 µs device-wide, overlapped with gathers).
//  2. Gather in 16-deep STATIC bursts: rows[] padded to a multiple of 16
//     with rows[0] (<=15 pad loads, same line -> L1-hot; corrected by one
//     subtract). 16 float2 = 32 VGPRs of in-flight data — no spill.
// Per-CU outstanding ~ up to 8 blk x 4 waves x 8 KB >> 22 KB BW*latency
// product -> BW-bound gather. Roofline: 134 MB embed+centroid+out over
// ~5 TB/s ~ 27 µs + scan/launch.

#define BATCH       32768
#define EMBED_DIM   1024
#define NUM_CLASSES 1000
#define FACTOR      0.3f
#define MAXR        128    // Poisson(32.8): max class count ~60
#define HALF_DIM    512

__global__ __launch_bounds__(256) void centroid_kernel(
    const float* __restrict__ embed,
    const int*   __restrict__ y,
    const float* __restrict__ centroid,
    float*       __restrict__ out)
{
    const int bid = blockIdx.x;
    const int c   = bid >> 1;        // class
    const int h   = bid & 1;         // which 512-dim half
    const int tid = threadIdx.x;
    const int d0  = h * HALF_DIM + tid * 2;   // this thread's 2 dims

    __shared__ int rows[MAXR];       // matched row indices for class c
    __shared__ int nmatch;

    if (tid == 0) nmatch = 0;

    // Hoisted centroid load — overlaps the scan.
    const size_t o = (size_t)c * EMBED_DIM + d0;
    const float2 cen = *reinterpret_cast<const float2*>(centroid + o);

    __syncthreads();

    // ---- Scan: 32768 labels, coalesced int4 (4 labels/thread/chunk).
    // y is 128 KB -> L2-resident after first touch.
    #pragma unroll 8
    for (int base = 0; base < BATCH; base += 1024) {
        const int idx = base + tid * 4;
        const int4 v = *reinterpret_cast<const int4*>(y + idx);
        if (v.x == c) { int p = atomicAdd(&nmatch, 1); rows[p] = idx + 0; }
        if (v.y == c) { int p = atomicAdd(&nmatch, 1); rows[p] = idx + 1; }
        if (v.z == c) { int p = atomicAdd(&nmatch, 1); rows[p] = idx + 2; }
        if (v.w == c) { int p = atomicAdd(&nmatch, 1); rows[p] = idx + 3; }
    }
    __syncthreads();

    const int m  = nmatch;                   // block-uniform (~33, max ~60)
    const int mp = (m + 15) & ~15;           // padded to multiple of 16

    // Pad with rows[0] (valid whenever mp > 0, i.e. m > 0): pad loads
    // re-hit one L1-resident row; corrected after the loop.
    if (tid >= m && tid < mp) rows[tid] = rows[0];
    __syncthreads();

    float2 accs[4];
    #pragma unroll
    for (int a = 0; a < 4; ++a) accs[a] = make_float2(0.f, 0.f);

    // ---- Gather: bursts of 16 static, independent float2 loads
    // (32 VGPRs in flight — fits; no runtime branches inside the burst).
    for (int j = 0; j < mp; j += 16) {
        float2 v[16];
        #pragma unroll
        for (int u = 0; u < 16; ++u) {
            const int r = rows[j + u];       // LDS broadcast — no conflict
            v[u] = *reinterpret_cast<const float2*>(
                embed + (size_t)r * EMBED_DIM + d0);
        }
        #pragma unroll
        for (int u = 0; u < 16; ++u) {
            accs[u & 3].x += v[u].x;
            accs[u & 3].y += v[u].y;
        }
    }

    // Remove pad contribution: (mp - m) copies of rows[0]'s value (L1 hit).
    if (mp > m) {
        const float pad = (float)(mp - m);
        const int r0 = rows[0];
        const float2 v0 = *reinterpret_cast<const float2*>(
            embed + (size_t)r0 * EMBED_DIM + d0);
        accs[0].x = fmaf(-pad, v0.x, accs[0].x);
        accs[0].y = fmaf(-pad, v0.y, accs[0].y);
    }

    float2 acc;
    acc.x = (accs[0].x + accs[1].x) + (accs[2].x + accs[3].x);
    acc.y = (accs[0].y + accs[1].y) + (accs[2].y + accs[3].y);

    // ---- Epilogue: mean, blend, store. m==0 -> 0*inf = NaN, matching ref.
    const float inv = 1.0f / (float)m;
    float2 res;
    res.x = FACTOR * (acc.x * inv) + (1.0f - FACTOR) * cen.x;
    res.y = FACTOR * (acc.y * inv) + (1.0f - FACTOR) * cen.y;
    *reinterpret_cast<float2*>(out + o) = res;
}

extern "C" void kernel_launch(void* const* d_in, const int* in_sizes, int n_in,
                              void* d_out, int out_size, void* d_ws, size_t ws_size,
                              hipStream_t stream) {
    const float* embed    = (const float*)d_in[0];  // [32768, 1024]
    const int*   y        = (const int*)d_in[1];    // [32768] int32
    const float* centroid = (const float*)d_in[2];  // [1000, 1024]
    float*       out      = (float*)d_out;          // [1000, 1024]

    centroid_kernel<<<NUM_CLASSES * 2, 256, 0, stream>>>(embed, y, centroid, out);
}

// Round 8
// 201.249 us; speedup vs baseline: 1.1998x; 1.0579x over previous
//
#include <hip/hip_runtime.h>

// Centroid update: per-class mean of embed rows, blended with old centroid.
//   sums[c,:] = sum_{i: y[i]==c} embed[i,:]
//   out[c,:]  = 0.3 * sums[c,:]/count[c] + 0.7 * centroid[c,:]
//
// v8 = the three counter-backed levers combined:
//  * v0's lesson (206 µs, best measured): INTERLEAVE scan and gather —
//    phase-separated variants (v3/v5/v7) idle HBM during the lockstep scan
//    and cluster at 212-213. Here: per-chunk (4096 labels) scan of chunk
//    k+1 overlaps the gather of chunk k via double-buffered row lists;
//    ONE barrier per chunk (8 total, vs v0's 96).
//  * v6's lesson (36% occ -> 2.08x BW of 9% occ): occupancy is the BW
//    lever. 2000 blocks (class x dim-half, float2/thread) -> 7.8 blk/CU,
//    ~31 waves/CU (~98% ceiling).
//  * v6/v7's lesson: keep in-flight state register-sized. Pad-to-4 static
//    float2 bursts = 8 VGPRs of data in flight, no spill (v6's 90 MB
//    scratch WRITE_SIZE disaster). ~31 waves x 4 x 512 B ~ 62 KB/CU
//    outstanding > 22 KB BW*latency product.
// Scan traffic 2000 x 128 KB = 256 MB of L2 reads, hidden under the gather
// stream. Gather: embed 128 MiB read exactly once device-wide (each block
// reads 512 B of each matched 4 KB row, halves disjoint).

#define BATCH       32768
#define EMBED_DIM   1024
#define NUM_CLASSES 1000
#define FACTOR      0.3f
#define HALF_DIM    512
#define CHUNK       4096   // labels per chunk; 8 chunks of 4 int4 per thread
#define NCHUNK      (BATCH / CHUNK)
#define MAXR        80     // per-chunk matches: Poisson(4.1), max ~20; 80 safe

__global__ __launch_bounds__(256) void centroid_kernel(
    const float* __restrict__ embed,
    const int*   __restrict__ y,
    const float* __restrict__ centroid,
    float*       __restrict__ out)
{
    const int bid = blockIdx.x;
    const int c   = bid >> 1;                 // class
    const int h   = bid & 1;                  // dim half
    const int tid = threadIdx.x;
    const int d0  = h * HALF_DIM + tid * 2;   // this thread's 2 dims

    __shared__ int rows[2][MAXR];             // double-buffered match lists
    __shared__ int nm[2];

    if (tid < 2) nm[tid] = 0;

    // Hoisted: centroid load overlaps everything.
    const size_t o = (size_t)c * EMBED_DIM + d0;
    const float2 cen = *reinterpret_cast<const float2*>(centroid + o);

    __syncthreads();

    // Scan one 4096-label chunk into buffer b. 4 coalesced int4 loads per
    // thread, independent -> pipelined. y is 128 KB, L2-resident.
#define SCAN(ck, b)                                                         \
    {                                                                       \
        const int base_ = (ck) * CHUNK + tid * 4;                           \
        _Pragma("unroll")                                                   \
        for (int q = 0; q < 4; ++q) {                                       \
            const int idx = base_ + q * 1024;                               \
            const int4 v = *reinterpret_cast<const int4*>(y + idx);         \
            if (v.x == c) { int p = atomicAdd(&nm[b], 1); rows[b][p] = idx + 0; } \
            if (v.y == c) { int p = atomicAdd(&nm[b], 1); rows[b][p] = idx + 1; } \
            if (v.z == c) { int p = atomicAdd(&nm[b], 1); rows[b][p] = idx + 2; } \
            if (v.w == c) { int p = atomicAdd(&nm[b], 1); rows[b][p] = idx + 3; } \
        }                                                                   \
    }

    // Prologue: fill buffer 0.
    SCAN(0, 0)
    __syncthreads();

    float2 acc0 = make_float2(0.f, 0.f);
    float2 acc1 = make_float2(0.f, 0.f);
    int count = 0;

    for (int k = 0; k < NCHUNK; ++k) {
        const int b = k & 1;
        const int m = nm[b];          // block-uniform, read before reset

        // Issue next chunk's scan first: its y-loads + LDS atomics target
        // the OTHER buffer and overlap the gather's global loads below.
        if (k + 1 < NCHUNK) SCAN(k + 1, b ^ 1)

        // Gather buffer b: pad to multiple of 4 with rows[b][0] (L1-hot
        // duplicate line), static 4-deep float2 bursts = 8 VGPRs in flight.
        const int mp = (m + 3) & ~3;
        for (int j = 0; j < mp; j += 4) {
            float2 v[4];
            #pragma unroll
            for (int u = 0; u < 4; ++u) {
                const int jj = j + u;
                const int r = rows[b][jj < m ? jj : 0];  // LDS broadcast
                v[u] = *reinterpret_cast<const float2*>(
                    embed + (size_t)r * EMBED_DIM + d0);
            }
            acc0.x += v[0].x; acc0.y += v[0].y;
            acc1.x += v[1].x; acc1.y += v[1].y;
            acc0.x += v[2].x; acc0.y += v[2].y;
            acc1.x += v[3].x; acc1.y += v[3].y;
        }
        // Remove pad contribution ((mp-m) copies of rows[b][0], L1 hit).
        if (mp > m) {
            const float pad = (float)(mp - m);
            const int r0 = rows[b][0];
            const float2 v0 = *reinterpret_cast<const float2*>(
                embed + (size_t)r0 * EMBED_DIM + d0);
            acc0.x = fmaf(-pad, v0.x, acc0.x);
            acc0.y = fmaf(-pad, v0.y, acc0.y);
        }
        count += m;

        if (tid == 0) nm[b] = 0;      // ready for chunk k+2
        __syncthreads();              // one barrier per chunk
    }

    // ---- Epilogue: mean, blend, store. count==0 -> 0*inf = NaN (matches ref).
    const float inv = 1.0f / (float)count;
    const float sx = acc0.x + acc1.x;
    const float sy = acc0.y + acc1.y;
    float2 res;
    res.x = FACTOR * (sx * inv) + (1.0f - FACTOR) * cen.x;
    res.y = FACTOR * (sy * inv) + (1.0f - FACTOR) * cen.y;
    *reinterpret_cast<float2*>(out + o) = res;
#undef SCAN
}

extern "C" void kernel_launch(void* const* d_in, const int* in_sizes, int n_in,
                              void* d_out, int out_size, void* d_ws, size_t ws_size,
                              hipStream_t stream) {
    const float* embed    = (const float*)d_in[0];  // [32768, 1024]
    const int*   y        = (const int*)d_in[1];    // [32768] int32
    const float* centroid = (const float*)d_in[2];  // [1000, 1024]
    float*       out      = (float*)d_out;          // [1000, 1024]

    centroid_kernel<<<NUM_CLASSES * 2, 256, 0, stream>>>(embed, y, centroid, out);
}